// Round 13
// baseline (31.620 us; speedup 1.0000x reference)
//
#include <hip/hip_runtime.h>
#include <hip/hip_bf16.h>

// DISCRIMINATOR EXPERIMENT on r9 (26.9us best): every output store issued
// TWICE (same addr, same value -> output identical; memory clobber between
// bursts prevents dead-store elimination). Marginal cost of +105MB decides:
//   fixed-overhead model: dur ~= 27 + 105MB/6.9TB/s ~= 42us
//   BW-cap model (3.9):   dur ~= 54us
//   cache-absorbed:       dur ~= 28-34us  -> NOT write-bound, pursue TLP
// out[t, e] = sum_r w[t,r] * B[r,e]; w from U0*U1*U2 gathers, B from V0*V1.

#define RANKK 32
#define EMB 128

typedef __attribute__((ext_vector_type(8))) short short8v;  // 8 bf16 = 4 VGPRs
typedef __attribute__((ext_vector_type(4))) float f32x4;

__device__ __forceinline__ short f2bf(float f) {
    union { __hip_bfloat16 h; short s; } u;
    u.h = __float2bfloat16(f);   // RNE
    return u.s;
}

struct G6 { float4 a0, a1, b0, b1, c0, c1; };

__device__ __forceinline__ G6 gather6(unsigned ui,
    const float* __restrict__ U0, const float* __restrict__ U1,
    const float* __restrict__ U2, int rb)
{
    const unsigned a   = ui / 5000u;
    const unsigned rem = ui - a * 5000u;
    const unsigned b   = rem / 50u;
    const unsigned c   = rem - b * 50u;
    const float4* p0 = (const float4*)(U0 + a * RANKK + rb);
    const float4* p1 = (const float4*)(U1 + b * RANKK + rb);
    const float4* p2 = (const float4*)(U2 + c * RANKK + rb);
    G6 r;
    r.a0 = p0[0]; r.a1 = p0[1];
    r.b0 = p1[0]; r.b1 = p1[1];
    r.c0 = p2[0]; r.c1 = p2[1];
    return r;
}

__device__ __forceinline__ short8v mkafrag(const G6& q) {
    float wv[8];
    wv[0]=q.a0.x*q.b0.x*q.c0.x; wv[1]=q.a0.y*q.b0.y*q.c0.y;
    wv[2]=q.a0.z*q.b0.z*q.c0.z; wv[3]=q.a0.w*q.b0.w*q.c0.w;
    wv[4]=q.a1.x*q.b1.x*q.c1.x; wv[5]=q.a1.y*q.b1.y*q.c1.y;
    wv[6]=q.a1.z*q.b1.z*q.c1.z; wv[7]=q.a1.w*q.b1.w*q.c1.w;
    short8v af;
    #pragma unroll
    for (int i = 0; i < 8; ++i) af[i] = f2bf(wv[i]);
    return af;
}

__global__ __launch_bounds__(256) void cpemb_mfma(
    const int* __restrict__ x,
    const float* __restrict__ U0, const float* __restrict__ U1,
    const float* __restrict__ U2,
    const float* __restrict__ V0, const float* __restrict__ V1,
    float* __restrict__ out, int ntok)
{
    const int tid  = threadIdx.x;
    const int lane = tid & 63;
    const int gw   = blockIdx.x * 4 + (tid >> 6);
    const int nw   = gridDim.x * 4;
    const int ngroups = (ntok + 15) >> 4;   // 16-token tiles

    const int t_l = lane & 15;
    const int g   = lane >> 4;
    const int rb  = g * 8;

    // ---- hoisted token-index loads ----
    unsigned ui[4];
    bool has[4];
    #pragma unroll
    for (int k = 0; k < 4; ++k) {
        int grp = gw + k * nw;
        has[k] = grp < ngroups;
        if (grp >= ngroups) grp = ngroups - 1;
        int tok = (grp << 4) + t_l;
        if (tok >= ntok) tok = ntok - 1;
        ui[k] = (unsigned)x[tok];
    }

    // ---- loop-invariant B-fragments ----
    float v1r[8];
    {
        const float4* p = (const float4*)(V1 + t_l * RANKK + rb);
        float4 lo = p[0], hi = p[1];
        v1r[0]=lo.x; v1r[1]=lo.y; v1r[2]=lo.z; v1r[3]=lo.w;
        v1r[4]=hi.x; v1r[5]=hi.y; v1r[6]=hi.z; v1r[7]=hi.w;
    }
    short8v bfrag[8];
    #pragma unroll
    for (int eb = 0; eb < 8; ++eb) {
        const float4* p = (const float4*)(V0 + eb * RANKK + rb);
        float4 lo = p[0], hi = p[1];
        float v0r[8] = {lo.x, lo.y, lo.z, lo.w, hi.x, hi.y, hi.z, hi.w};
        #pragma unroll
        for (int i = 0; i < 8; ++i)
            bfrag[eb][i] = f2bf(v0r[i] * v1r[i]);
    }

    if (!has[0]) return;

    G6 cg = gather6(ui[0], U0, U1, U2, rb);

    #pragma unroll
    for (int k = 0; k < 4; ++k) {
        if (!has[k]) break;

        const bool pn = (k + 1 < 4) && has[k + 1];
        G6 ng;
        if (pn) ng = gather6(ui[k + 1], U0, U1, U2, rb);

        short8v afrag = mkafrag(cg);

        const int grp = gw + k * nw;
        const int t0  = grp << 4;
        const bool ok = (t0 + t_l) < ntok;
        float* ob = out + (size_t)(t0 + g * 4) * EMB + t_l;

        f32x4 acc[8];
        #pragma unroll
        for (int eb = 0; eb < 8; ++eb) {
            f32x4 z = {0.f, 0.f, 0.f, 0.f};
            acc[eb] = __builtin_amdgcn_mfma_f32_16x16x32_bf16(afrag, bfrag[eb], z, 0, 0, 0);
        }

        // ---- burst 1 ----
        if (ok) {
            #pragma unroll
            for (int eb = 0; eb < 8; ++eb)
                #pragma unroll
                for (int j = 0; j < 4; ++j)
                    ob[(size_t)j * EMB + eb * 16] = acc[eb][j];
        }
        // keep burst 1 observable so DSE can't drop it
        asm volatile("" ::: "memory");
        // ---- burst 2 (same addresses, same values: output unchanged) ----
        if (ok) {
            #pragma unroll
            for (int eb = 0; eb < 8; ++eb)
                #pragma unroll
                for (int j = 0; j < 4; ++j)
                    ob[(size_t)j * EMB + eb * 16] = acc[eb][j];
        }

        if (pn) cg = ng;
    }
}

extern "C" void kernel_launch(void* const* d_in, const int* in_sizes, int n_in,
                              void* d_out, int out_size, void* d_ws, size_t ws_size,
                              hipStream_t stream) {
    const int*   x  = (const int*)d_in[0];
    const float* U0 = (const float*)d_in[1];
    const float* U1 = (const float*)d_in[2];
    const float* U2 = (const float*)d_in[3];
    const float* V0 = (const float*)d_in[4];
    const float* V1 = (const float*)d_in[5];
    float* out = (float*)d_out;

    const int ntok = in_sizes[0];
    const int blocks = 1024;

    cpemb_mfma<<<blocks, 256, 0, stream>>>(x, U0, U1, U2, V0, V1, out, ntok);
}

// Round 14
// 26.337 us; speedup vs baseline: 1.2006x; 1.2006x over previous
//
#include <hip/hip_runtime.h>
#include <hip/hip_bf16.h>

// CP tensorized embedding gather via MFMA — deep per-wave amortization:
// out[t, e] = sum_r w[t,r] * B[r,e]
//   w[t,r] = U0[a,r]*U1[b,r]*U2[c,r], idx=x[t], a=idx/5000, b=(idx/50)%100, c=idx%50
//   B[r,e] = V0[e>>4,r]*V1[e&15,r]
// Evidence: r13 discriminator -> duplicate stores cost 22 TB/s marginal (L2
// absorbed) => NOT store/HBM-bound; latency-bound per wave. Fit of r4 vs r9
// gives per-wave setup ~2.1x per-tile cost => amortize: 2048 waves x ~6.25
// tiles (vs r9's 4096 x 3.1), with a 2-deep pipeline so the longer loop stays
// stall-free: gathers for tile k+1 and the x-index load for tile k+2 are both
// issued BEFORE tile k's stores (in-order vmcnt => their waits never drain
// the store FIFO). Math, layout, stores identical to r9.

#define RANKK 32
#define EMB 128

typedef __attribute__((ext_vector_type(8))) short short8v;  // 8 bf16 = 4 VGPRs
typedef __attribute__((ext_vector_type(4))) float f32x4;

__device__ __forceinline__ short f2bf(float f) {
    union { __hip_bfloat16 h; short s; } u;
    u.h = __float2bfloat16(f);   // RNE
    return u.s;
}

struct G6 { float4 a0, a1, b0, b1, c0, c1; };

__device__ __forceinline__ G6 gather6(unsigned ui,
    const float* __restrict__ U0, const float* __restrict__ U1,
    const float* __restrict__ U2, int rb)
{
    const unsigned a   = ui / 5000u;
    const unsigned rem = ui - a * 5000u;
    const unsigned b   = rem / 50u;
    const unsigned c   = rem - b * 50u;
    const float4* p0 = (const float4*)(U0 + a * RANKK + rb);
    const float4* p1 = (const float4*)(U1 + b * RANKK + rb);
    const float4* p2 = (const float4*)(U2 + c * RANKK + rb);
    G6 r;
    r.a0 = p0[0]; r.a1 = p0[1];
    r.b0 = p1[0]; r.b1 = p1[1];
    r.c0 = p2[0]; r.c1 = p2[1];
    return r;
}

__device__ __forceinline__ short8v mkafrag(const G6& q) {
    float wv[8];
    wv[0]=q.a0.x*q.b0.x*q.c0.x; wv[1]=q.a0.y*q.b0.y*q.c0.y;
    wv[2]=q.a0.z*q.b0.z*q.c0.z; wv[3]=q.a0.w*q.b0.w*q.c0.w;
    wv[4]=q.a1.x*q.b1.x*q.c1.x; wv[5]=q.a1.y*q.b1.y*q.c1.y;
    wv[6]=q.a1.z*q.b1.z*q.c1.z; wv[7]=q.a1.w*q.b1.w*q.c1.w;
    short8v af;
    #pragma unroll
    for (int i = 0; i < 8; ++i) af[i] = f2bf(wv[i]);
    return af;
}

__global__ __launch_bounds__(256) void cpemb_mfma(
    const int* __restrict__ x,
    const float* __restrict__ U0, const float* __restrict__ U1,
    const float* __restrict__ U2,
    const float* __restrict__ V0, const float* __restrict__ V1,
    float* __restrict__ out, int ntok)
{
    const int tid  = threadIdx.x;
    const int lane = tid & 63;
    const int gw   = blockIdx.x * 4 + (tid >> 6);
    const int nw   = gridDim.x * 4;
    const int ngroups = (ntok + 15) >> 4;   // 16-token tiles

    const int t_l = lane & 15;   // token-within-tile (A row / D col-partner)
    const int g   = lane >> 4;   // k-chunk group; D row block (g*4+j)
    const int rb  = g * 8;       // rank base (k = rb..rb+7)

    if (gw >= ngroups) return;

    // ---- loop-invariant table fragments (MFMA B operand):
    // col e = eb*16 + t_l -> V1 row = t_l (fixed), V0 row = eb (uniform).
    float v1r[8];
    {
        const float4* p = (const float4*)(V1 + t_l * RANKK + rb);
        float4 lo = p[0], hi = p[1];
        v1r[0]=lo.x; v1r[1]=lo.y; v1r[2]=lo.z; v1r[3]=lo.w;
        v1r[4]=hi.x; v1r[5]=hi.y; v1r[6]=hi.z; v1r[7]=hi.w;
    }
    short8v bfrag[8];
    #pragma unroll
    for (int eb = 0; eb < 8; ++eb) {
        const float4* p = (const float4*)(V0 + eb * RANKK + rb);
        float4 lo = p[0], hi = p[1];
        float v0r[8] = {lo.x, lo.y, lo.z, lo.w, hi.x, hi.y, hi.z, hi.w};
        #pragma unroll
        for (int i = 0; i < 8; ++i)
            bfrag[eb][i] = f2bf(v0r[i] * v1r[i]);
    }

    // ---- prologue: x + gathers for tile gw; x for tile gw+nw ----
    G6 gcur;
    {
        int tok = (gw << 4) + t_l;
        if (tok >= ntok) tok = ntok - 1;
        gcur = gather6((unsigned)x[tok], U0, U1, U2, rb);
    }
    unsigned ui_n = 0u;
    if (gw + nw < ngroups) {
        int tn = ((gw + nw) << 4) + t_l;
        if (tn >= ntok) tn = ntok - 1;
        ui_n = (unsigned)x[tn];
    }

    for (int grp = gw; grp < ngroups; grp += nw) {
        // ---- afrag for current tile: waits ONLY on gcur's 6 loads
        // (issued before last iteration's stores -> no store drain).
        short8v afrag = mkafrag(gcur);

        // ---- pipeline refill, all issued BEFORE this tile's stores:
        const int  gnx = grp + nw;
        const bool hn  = gnx < ngroups;
        G6 gn;
        if (hn) gn = gather6(ui_n, U0, U1, U2, rb);   // waits ui_n (pre-store load)
        const int gn2 = grp + 2 * nw;
        if (gn2 < ngroups) {                           // issue x for tile k+2
            int t2 = (gn2 << 4) + t_l;
            if (t2 >= ntok) t2 = ntok - 1;
            ui_n = (unsigned)x[t2];
        }

        // ---- 8 MFMAs + stores (r2/r9 exact layout: row=token, col=e)
        const int t0  = grp << 4;
        const bool ok = (t0 + t_l) < ntok;
        float* ob = out + (size_t)(t0 + g * 4) * EMB + t_l;
        #pragma unroll
        for (int eb = 0; eb < 8; ++eb) {
            f32x4 z = {0.f, 0.f, 0.f, 0.f};
            f32x4 acc = __builtin_amdgcn_mfma_f32_16x16x32_bf16(afrag, bfrag[eb], z, 0, 0, 0);
            if (ok) {
                #pragma unroll
                for (int j = 0; j < 4; ++j)
                    ob[(size_t)j * EMB + eb * 16] = acc[j];
            }
        }

        if (hn) gcur = gn;
    }
}

extern "C" void kernel_launch(void* const* d_in, const int* in_sizes, int n_in,
                              void* d_out, int out_size, void* d_ws, size_t ws_size,
                              hipStream_t stream) {
    const int*   x  = (const int*)d_in[0];
    const float* U0 = (const float*)d_in[1];
    const float* U1 = (const float*)d_in[2];
    const float* U2 = (const float*)d_in[3];
    const float* V0 = (const float*)d_in[4];
    const float* V1 = (const float*)d_in[5];
    float* out = (float*)d_out;

    const int ntok = in_sizes[0];   // 204800 -> 12800 tiles
    // 512 blocks = 2048 waves -> ~6.25 tiles/wave (2x r9's amortization),
    // 2 waves/SIMD residency; front-end fully pipelined so depth suffices.
    const int blocks = 512;

    cpemb_mfma<<<blocks, 256, 0, stream>>>(x, U0, U1, U2, V0, V1, out, ntok);
}